// Round 9
// baseline (177.750 us; speedup 1.0000x reference)
//
#include <hip/hip_runtime.h>
#include <hip/hip_bf16.h>

#define BB 2
#define NN 4096
#define LL 256
#define DD 2048
#define CC 6
#define EPSF 1e-6f
#define FGRID 512

typedef float floatx4 __attribute__((ext_vector_type(4)));

__device__ __forceinline__ float dot4(float4 a, float4 b) {
    return a.x * b.x + a.y * b.y + a.z * b.z + a.w * b.w;
}

// Single-use grid barrier: each barrier has its OWN counter (zeroed by
// hipMemsetAsync before launch). Arrive via device-scope atomicAdd, then
// spin (s_sleep backoff) until all blocks arrived. threadfence = release
// before arrive / acquire after.
__device__ __forceinline__ void gbar(int* cnt, int nb) {
    __syncthreads();
    if (threadIdx.x == 0) {
        __threadfence();
        __hip_atomic_fetch_add(cnt, 1, __ATOMIC_ACQ_REL, __HIP_MEMORY_SCOPE_AGENT);
        while (__hip_atomic_load(cnt, __ATOMIC_RELAXED, __HIP_MEMORY_SCOPE_AGENT) < nb)
            __builtin_amdgcn_s_sleep(8);
        __threadfence();
    }
    __syncthreads();
}

// ===========================================================================
// Fused front-end: A cluster -> B creps -> C vfuse -> D rmsout, one dispatch.
__global__ __launch_bounds__(256, 4) void k_front(
    const float* __restrict__ te, const float* __restrict__ Wc,
    const float* __restrict__ Wv, const float* __restrict__ Wo,
    const float* __restrict__ blendw, const float* __restrict__ sgate,
    const int* __restrict__ issur, const float* __restrict__ nw,
    float* __restrict__ cw, float* __restrict__ cr,
    float* __restrict__ fused, float* __restrict__ o,
    int* __restrict__ bars)
{
    __shared__ float smem[3072];             // 12.3 KB, aliased per phase
    __shared__ float sredC[2][2][BB][2][CC];
    __shared__ float sredD0[4][BB];
    __shared__ float sscale[BB];
    __shared__ float sredD1[2][2][BB][2];
    const int bid = blockIdx.x, tid = threadIdx.x;
    const int lane = tid & 63, wid = tid >> 6;

    //--- Phase A: cluster softmax, one (b,l) row per block (512 rows) ------
    {
        const float4* t4 = (const float4*)(te + (size_t)bid * DD);
        float p[CC];
#pragma unroll
        for (int c = 0; c < CC; ++c) p[c] = 0.f;
#pragma unroll
        for (int it = 0; it < 2; ++it) {
            const int i = it * 256 + tid;
            const float4 xv = t4[i];
#pragma unroll
            for (int c = 0; c < CC; ++c)
                p[c] += dot4(xv, ((const float4*)(Wc + (size_t)c * DD))[i]);
        }
#pragma unroll
        for (int c = 0; c < CC; ++c)
            for (int off = 32; off; off >>= 1) p[c] += __shfl_down(p[c], off);
        if (lane == 0) {
#pragma unroll
            for (int c = 0; c < CC; ++c) smem[wid * CC + c] = p[c];
        }
        __syncthreads();
        if (tid == 0) {
            float lg[CC], m = -1e30f;
#pragma unroll
            for (int c = 0; c < CC; ++c) {
                lg[c] = smem[c] + smem[CC + c] + smem[2 * CC + c] + smem[3 * CC + c];
                m = fmaxf(m, lg[c]);
            }
            float s = 0.f;
#pragma unroll
            for (int c = 0; c < CC; ++c) { lg[c] = __expf(lg[c] - m); s += lg[c]; }
            const float inv = 1.f / s;
#pragma unroll
            for (int c = 0; c < CC; ++c) cw[bid * CC + c] = lg[c] * inv;
        }
    }
    gbar(bars + 0, FGRID);

    //--- Phase B: concept_reps, 128 active blocks --------------------------
    if (bid < 128) {
        const int b = bid >> 6;
        const int d0 = (bid & 63) * 32;
        const int dl = tid & 31;             // d within slice
        const int lc = tid >> 5;             // l-chunk 0..7
        float* scw  = smem;                  // 1536 floats
        float* sacc = smem + 1536;           // 8*32*6 = 1536 floats
        for (int i = tid; i < LL * CC; i += 256) scw[i] = cw[b * LL * CC + i];
        __syncthreads();
        float acc[CC];
#pragma unroll
        for (int c = 0; c < CC; ++c) acc[c] = 0.f;
        const float* tb = te + ((size_t)b * LL + lc * 32) * DD + d0 + dl;
        for (int l = 0; l < 32; ++l) {
            const float xv = tb[(size_t)l * DD];
            const int gl = lc * 32 + l;
#pragma unroll
            for (int c = 0; c < CC; ++c) acc[c] = fmaf(scw[gl * CC + c], xv, acc[c]);
        }
#pragma unroll
        for (int c = 0; c < CC; ++c) sacc[(lc * 32 + dl) * CC + c] = acc[c];
        __syncthreads();
        if (tid < 32) {
#pragma unroll
            for (int c = 0; c < CC; ++c) {
                float s = 0.f;
#pragma unroll
                for (int k = 0; k < 8; ++k) s += sacc[(k * 32 + tid) * CC + c];
                cr[((size_t)b * CC + c) * DD + d0 + tid] = s;
            }
        }
    }
    gbar(bars + 1, FGRID);

    //--- Phase C: v = cr.Wv^T + blend/var fuse -> fused --------------------
    {
        const int p = wid >> 1, h = wid & 1;
        const int e0 = bid * 4 + p * 2;
        float acc[BB][2][CC];
#pragma unroll
        for (int b = 0; b < BB; ++b)
#pragma unroll
            for (int j = 0; j < 2; ++j)
#pragma unroll
                for (int c = 0; c < CC; ++c) acc[b][j][c] = 0.f;
#pragma unroll
        for (int it = 0; it < 4; ++it) {
            const int d = h * 1024 + it * 256 + lane * 4;
            const float4 w0 = *(const float4*)(Wv + (size_t)e0 * DD + d);
            const float4 w1 = *(const float4*)(Wv + (size_t)(e0 + 1) * DD + d);
#pragma unroll
            for (int b = 0; b < BB; ++b)
#pragma unroll
                for (int c = 0; c < CC; ++c) {
                    const float4 cv = *(const float4*)(cr + ((size_t)b * CC + c) * DD + d);
                    acc[b][0][c] += dot4(cv, w0);
                    acc[b][1][c] += dot4(cv, w1);
                }
        }
#pragma unroll
        for (int b = 0; b < BB; ++b)
#pragma unroll
            for (int j = 0; j < 2; ++j)
#pragma unroll
                for (int c = 0; c < CC; ++c)
                    for (int off = 32; off; off >>= 1)
                        acc[b][j][c] += __shfl_down(acc[b][j][c], off);
        if (lane == 0) {
#pragma unroll
            for (int b = 0; b < BB; ++b)
#pragma unroll
                for (int j = 0; j < 2; ++j)
#pragma unroll
                    for (int c = 0; c < CC; ++c) sredC[p][h][b][j][c] = acc[b][j][c];
        }
        __syncthreads();
        if ((wid & 1) == 0 && lane == 0) {
            float bw[CC], m = -1e30f;
#pragma unroll
            for (int c = 0; c < CC; ++c) { bw[c] = blendw[c]; m = fmaxf(m, bw[c]); }
            float s = 0.f;
#pragma unroll
            for (int c = 0; c < CC; ++c) { bw[c] = __expf(bw[c] - m); s += bw[c]; }
            const float inv = 1.f / s;
#pragma unroll
            for (int c = 0; c < CC; ++c) bw[c] *= inv;
            const float gate = 1.f / (1.f + __expf(-sgate[0]));
            const int sur = issur[0];
#pragma unroll
            for (int b = 0; b < BB; ++b)
#pragma unroll
                for (int j = 0; j < 2; ++j) {
                    float vv[CC];
#pragma unroll
                    for (int c = 0; c < CC; ++c)
                        vv[c] = sredC[p][0][b][j][c] + sredC[p][1][b][j][c];
                    float f = 0.f, mean = 0.f;
#pragma unroll
                    for (int c = 0; c < CC; ++c) { f = fmaf(bw[c], vv[c], f); mean += vv[c]; }
                    mean *= (1.f / CC);
                    float var = 0.f;
#pragma unroll
                    for (int c = 0; c < CC; ++c) {
                        const float dv = vv[c] - mean;
                        var = fmaf(dv, dv, var);
                    }
                    var *= (1.f / (CC - 1));             // ddof=1
                    if (sur) f = fmaf(gate * var, 0.3f, f);
                    fused[b * DD + e0 + j] = f;
                }
        }
    }
    gbar(bars + 2, FGRID);

    //--- Phase D: RMS scales (per-block recompute) + out-proj GEMV ---------
    {
        float ss[BB];
#pragma unroll
        for (int b = 0; b < BB; ++b) ss[b] = 0.f;
#pragma unroll
        for (int k = 0; k < DD / 256; ++k) {
            const int d = k * 256 + tid;
#pragma unroll
            for (int b = 0; b < BB; ++b) {
                const float v = fused[b * DD + d];
                ss[b] = fmaf(v, v, ss[b]);
            }
        }
#pragma unroll
        for (int b = 0; b < BB; ++b)
            for (int off = 32; off; off >>= 1) ss[b] += __shfl_down(ss[b], off);
        if (lane == 0) {
#pragma unroll
            for (int b = 0; b < BB; ++b) sredD0[wid][b] = ss[b];
        }
        __syncthreads();
        if (tid == 0) {
#pragma unroll
            for (int b = 0; b < BB; ++b) {
                const float tot = sredD0[0][b] + sredD0[1][b] + sredD0[2][b] + sredD0[3][b];
                sscale[b] = rsqrtf(tot * (1.f / DD) + EPSF);
            }
        }
        __syncthreads();
        const int p = wid >> 1, h = wid & 1;
        const int e0 = bid * 4 + p * 2;
        float acc[BB][2];
#pragma unroll
        for (int b = 0; b < BB; ++b)
#pragma unroll
            for (int j = 0; j < 2; ++j) acc[b][j] = 0.f;
#pragma unroll
        for (int it = 0; it < 4; ++it) {
            const int d = h * 1024 + it * 256 + lane * 4;
            const float4 nv = *(const float4*)(nw + d);
            float4 w0 = *(const float4*)(Wo + (size_t)e0 * DD + d);
            float4 w1 = *(const float4*)(Wo + (size_t)(e0 + 1) * DD + d);
            w0.x *= nv.x; w0.y *= nv.y; w0.z *= nv.z; w0.w *= nv.w;
            w1.x *= nv.x; w1.y *= nv.y; w1.z *= nv.z; w1.w *= nv.w;
#pragma unroll
            for (int b = 0; b < BB; ++b) {
                const float4 fv = *(const float4*)(fused + (size_t)b * DD + d);
                acc[b][0] += dot4(fv, w0);
                acc[b][1] += dot4(fv, w1);
            }
        }
#pragma unroll
        for (int b = 0; b < BB; ++b)
#pragma unroll
            for (int j = 0; j < 2; ++j)
                for (int off = 32; off; off >>= 1) acc[b][j] += __shfl_down(acc[b][j], off);
        if (lane == 0) {
#pragma unroll
            for (int b = 0; b < BB; ++b)
#pragma unroll
                for (int j = 0; j < 2; ++j) sredD1[p][h][b][j] = acc[b][j];
        }
        __syncthreads();
        if ((wid & 1) == 0 && lane == 0) {
#pragma unroll
            for (int b = 0; b < BB; ++b)
#pragma unroll
                for (int j = 0; j < 2; ++j)
                    o[b * DD + e0 + j] = (sredD1[p][0][b][j] + sredD1[p][1][b][j]) * sscale[b];
        }
    }
}

// ---------------------------------------------------------------------------
// K_add: out[b,n,e] = x[b,n,e] + o[b,e]. Cacheable x read, nontemporal store.
__global__ __launch_bounds__(256) void k_add(const float* __restrict__ x,
                                             const float* __restrict__ o,
                                             float* __restrict__ out) {
    const size_t total4 = (size_t)BB * NN * DD / 4;   // 2^22
    const floatx4* x4 = (const floatx4*)x;
    const floatx4* o4 = (const floatx4*)o;
    floatx4* out4 = (floatx4*)out;
    for (size_t f = (size_t)blockIdx.x * 256 + threadIdx.x; f < total4;
         f += (size_t)2048 * 256) {
        const int e4 = (int)(f & (DD / 4 - 1));
        const int b = (int)(f >> 21);                 // NN*DD/4 = 2^21
        const floatx4 xv = x4[f];                     // cacheable read
        const floatx4 ov = o4[b * (DD / 4) + e4];
        const floatx4 r = xv + ov;
        __builtin_nontemporal_store(r, &out4[f]);     // streaming write
    }
}

extern "C" void kernel_launch(void* const* d_in, const int* in_sizes, int n_in,
                              void* d_out, int out_size, void* d_ws, size_t ws_size,
                              hipStream_t stream) {
    const float* x  = (const float*)d_in[0];
    const float* te = (const float*)d_in[1];
    const float* Wc = (const float*)d_in[2];
    // d_in[3] = Wq, d_in[4] = Wk : unused (softmax over a single key == 1)
    const float* Wv = (const float*)d_in[5];
    const float* Wo = (const float*)d_in[6];
    const float* bw = (const float*)d_in[7];
    const float* sg = (const float*)d_in[8];
    const float* nw = (const float*)d_in[9];
    const int* isur = (const int*)d_in[10];
    float* out = (float*)d_out;

    float* ws     = (float*)d_ws;
    float* cw     = ws;                       // B*L*C  = 3072 (pad to 4096)
    float* cr     = ws + 4096;                // B*C*D  = 24576
    float* fusedv = ws + 4096 + 24576;        // B*D    = 4096
    float* o      = fusedv + 4096;            // B*D    = 4096
    int*   bars   = (int*)(o + 4096);         // 3 single-use barrier counters

    hipMemsetAsync(bars, 0, 3 * sizeof(int), stream);   // capturable
    void* args[] = { (void*)&te, (void*)&Wc, (void*)&Wv, (void*)&Wo,
                     (void*)&bw, (void*)&sg, (void*)&isur, (void*)&nw,
                     (void*)&cw, (void*)&cr, (void*)&fusedv, (void*)&o,
                     (void*)&bars };
    hipLaunchKernelGGL(k_front, dim3(FGRID), dim3(256), 0, stream,
                       te, Wc, Wv, Wo, bw, sg, isur, nw, cw, cr, fusedv, o, bars);
    (void)args;
    hipLaunchKernelGGL(k_add, dim3(2048), dim3(256), 0, stream, x, o, out);
}

// Round 10
// 53.574 us; speedup vs baseline: 3.3179x; 3.3179x over previous
//
#include <hip/hip_runtime.h>
#include <hip/hip_bf16.h>

#define BB 2
#define NN 4096
#define LL 256
#define DD 2048
#define CC 6
#define EPSF 1e-6f

typedef float floatx4 __attribute__((ext_vector_type(4)));

__device__ __forceinline__ float dot4(float4 a, float4 b) {
    return a.x * b.x + a.y * b.y + a.z * b.z + a.w * b.w;
}
__device__ __forceinline__ float dot4x(float4 a, floatx4 b) {
    return a.x * b.x + a.y * b.y + a.z * b.z + a.w * b.w;
}

// ---------------------------------------------------------------------------
// K1: cluster softmax -> cw (B,L,C). One block per (b,l) row. (R2-proven)
//     te/Wc cached (te re-read by creps; Wc shared by all blocks).
__global__ __launch_bounds__(256) void k_cluster(const float* __restrict__ te,
                                                 const float* __restrict__ Wc,
                                                 float* __restrict__ cw) {
    const int tid = threadIdx.x;
    const int row = blockIdx.x;              // b*LL + l
    const float4* t4 = (const float4*)(te + (size_t)row * DD);
    float p[CC];
#pragma unroll
    for (int c = 0; c < CC; ++c) p[c] = 0.f;
#pragma unroll
    for (int it = 0; it < 2; ++it) {
        const int i = it * 256 + tid;
        const float4 xv = t4[i];
#pragma unroll
        for (int c = 0; c < CC; ++c)
            p[c] += dot4(xv, ((const float4*)(Wc + (size_t)c * DD))[i]);
    }
#pragma unroll
    for (int c = 0; c < CC; ++c)
        for (int off = 32; off; off >>= 1) p[c] += __shfl_down(p[c], off);
    __shared__ float sred[4][CC];
    const int lane = tid & 63, wid = tid >> 6;
    if (lane == 0) {
#pragma unroll
        for (int c = 0; c < CC; ++c) sred[wid][c] = p[c];
    }
    __syncthreads();
    if (tid == 0) {
        float lg[CC], m = -1e30f;
#pragma unroll
        for (int c = 0; c < CC; ++c) {
            lg[c] = sred[0][c] + sred[1][c] + sred[2][c] + sred[3][c];
            m = fmaxf(m, lg[c]);
        }
        float s = 0.f;
#pragma unroll
        for (int c = 0; c < CC; ++c) { lg[c] = __expf(lg[c] - m); s += lg[c]; }
        const float inv = 1.f / s;
#pragma unroll
        for (int c = 0; c < CC; ++c) cw[row * CC + c] = lg[c] * inv;
    }
}

// ---------------------------------------------------------------------------
// K2: concept_reps -> cr (B,C,D). 128 blocks. te loaded NONTEMPORAL (last
//     reader of te this replay; each element read by exactly one thread).
__global__ __launch_bounds__(256) void k_creps(const float* __restrict__ te,
                                               const float* __restrict__ cw,
                                               float* __restrict__ cr) {
    const int tid = threadIdx.x;
    const int b = blockIdx.x >> 6;
    const int d0 = (blockIdx.x & 63) * 32;
    const int dl = tid & 31;                 // d within slice
    const int lc = tid >> 5;                 // l-chunk 0..7
    __shared__ float scw[LL * CC];           // 6 KB
    __shared__ float sacc[8][32][CC];        // 6 KB
    for (int i = tid; i < LL * CC; i += 256) scw[i] = cw[b * LL * CC + i];
    __syncthreads();
    float acc[CC];
#pragma unroll
    for (int c = 0; c < CC; ++c) acc[c] = 0.f;
    const float* tb = te + ((size_t)b * LL + lc * 32) * DD + d0 + dl;
    for (int l = 0; l < 32; ++l) {
        const float xv = __builtin_nontemporal_load(&tb[(size_t)l * DD]);
        const int gl = lc * 32 + l;
#pragma unroll
        for (int c = 0; c < CC; ++c) acc[c] = fmaf(scw[gl * CC + c], xv, acc[c]);
    }
#pragma unroll
    for (int c = 0; c < CC; ++c) sacc[lc][dl][c] = acc[c];
    __syncthreads();
    if (tid < 32) {
#pragma unroll
        for (int c = 0; c < CC; ++c) {
            float s = 0.f;
#pragma unroll
            for (int k = 0; k < 8; ++k) s += sacc[k][tid][c];
            cr[((size_t)b * CC + c) * DD + d0 + tid] = s;
        }
    }
}

// ---------------------------------------------------------------------------
// K3: v = cr.Wv^T + blend-softmax + unbiased-var gate -> fused (B,D).
//     512 blocks; wave = (pair p, half h). Wv NONTEMPORAL (each row read by
//     exactly one wave); cr stays cached (shared by all 512 blocks).
__global__ __launch_bounds__(256) void k_vfuse(const float* __restrict__ cr,
                                               const float* __restrict__ Wv,
                                               const float* __restrict__ blendw,
                                               const float* __restrict__ sgate,
                                               const int* __restrict__ issur,
                                               float* __restrict__ fused) {
    const int tid = threadIdx.x;
    const int lane = tid & 63, wid = tid >> 6;
    const int p = wid >> 1, h = wid & 1;
    const int e0 = blockIdx.x * 4 + p * 2;   // this pair's 2 e-columns
    float acc[BB][2][CC];
#pragma unroll
    for (int b = 0; b < BB; ++b)
#pragma unroll
        for (int j = 0; j < 2; ++j)
#pragma unroll
            for (int c = 0; c < CC; ++c) acc[b][j][c] = 0.f;
#pragma unroll
    for (int it = 0; it < 4; ++it) {
        const int d = h * 1024 + it * 256 + lane * 4;
        const floatx4 w0 = __builtin_nontemporal_load(
            (const floatx4*)(Wv + (size_t)e0 * DD + d));
        const floatx4 w1 = __builtin_nontemporal_load(
            (const floatx4*)(Wv + (size_t)(e0 + 1) * DD + d));
#pragma unroll
        for (int b = 0; b < BB; ++b)
#pragma unroll
            for (int c = 0; c < CC; ++c) {
                const float4 cv = *(const float4*)(cr + ((size_t)b * CC + c) * DD + d);
                acc[b][0][c] += dot4x(cv, w0);
                acc[b][1][c] += dot4x(cv, w1);
            }
    }
#pragma unroll
    for (int b = 0; b < BB; ++b)
#pragma unroll
        for (int j = 0; j < 2; ++j)
#pragma unroll
            for (int c = 0; c < CC; ++c)
                for (int off = 32; off; off >>= 1)
                    acc[b][j][c] += __shfl_down(acc[b][j][c], off);
    __shared__ float sred[2][2][BB][2][CC];
    if (lane == 0) {
#pragma unroll
        for (int b = 0; b < BB; ++b)
#pragma unroll
            for (int j = 0; j < 2; ++j)
#pragma unroll
                for (int c = 0; c < CC; ++c) sred[p][h][b][j][c] = acc[b][j][c];
    }
    __syncthreads();
    if (h == 0 && lane == 0) {
        float bw[CC], m = -1e30f;
#pragma unroll
        for (int c = 0; c < CC; ++c) { bw[c] = blendw[c]; m = fmaxf(m, bw[c]); }
        float s = 0.f;
#pragma unroll
        for (int c = 0; c < CC; ++c) { bw[c] = __expf(bw[c] - m); s += bw[c]; }
        const float inv = 1.f / s;
#pragma unroll
        for (int c = 0; c < CC; ++c) bw[c] *= inv;
        const float gate = 1.f / (1.f + __expf(-sgate[0]));
        const int sur = issur[0];
#pragma unroll
        for (int b = 0; b < BB; ++b)
#pragma unroll
            for (int j = 0; j < 2; ++j) {
                float vv[CC];
#pragma unroll
                for (int c = 0; c < CC; ++c)
                    vv[c] = sred[p][0][b][j][c] + sred[p][1][b][j][c];
                float f = 0.f, mean = 0.f;
#pragma unroll
                for (int c = 0; c < CC; ++c) { f = fmaf(bw[c], vv[c], f); mean += vv[c]; }
                mean *= (1.f / CC);
                float var = 0.f;
#pragma unroll
                for (int c = 0; c < CC; ++c) {
                    const float dv = vv[c] - mean;
                    var = fmaf(dv, dv, var);
                }
                var *= (1.f / (CC - 1));     // ddof=1
                if (sur) f = fmaf(gate * var, 0.3f, f);
                fused[b * DD + e0 + j] = f;
            }
    }
}

// ---------------------------------------------------------------------------
// K4: RMS scales (per-block recompute) + out-proj GEMV. Wo NONTEMPORAL
//     (single-reader rows); fused/nw cached (shared).
__global__ __launch_bounds__(256) void k_rmsout(const float* __restrict__ fused,
                                                const float* __restrict__ nw,
                                                const float* __restrict__ Wo,
                                                float* __restrict__ o) {
    const int tid = threadIdx.x;
    const int lane = tid & 63, wid = tid >> 6;
    float ss[BB];
#pragma unroll
    for (int b = 0; b < BB; ++b) ss[b] = 0.f;
#pragma unroll
    for (int k = 0; k < DD / 256; ++k) {
        const int d = k * 256 + tid;
#pragma unroll
        for (int b = 0; b < BB; ++b) {
            const float v = fused[b * DD + d];
            ss[b] = fmaf(v, v, ss[b]);
        }
    }
#pragma unroll
    for (int b = 0; b < BB; ++b)
        for (int off = 32; off; off >>= 1) ss[b] += __shfl_down(ss[b], off);
    __shared__ float sred0[4][BB];
    __shared__ float sscale[BB];
    if (lane == 0) {
#pragma unroll
        for (int b = 0; b < BB; ++b) sred0[wid][b] = ss[b];
    }
    __syncthreads();
    if (tid == 0) {
#pragma unroll
        for (int b = 0; b < BB; ++b) {
            const float tot = sred0[0][b] + sred0[1][b] + sred0[2][b] + sred0[3][b];
            sscale[b] = rsqrtf(tot * (1.f / DD) + EPSF);
        }
    }
    __syncthreads();
    const int p = wid >> 1, h = wid & 1;
    const int e0 = blockIdx.x * 4 + p * 2;
    float acc[BB][2];
#pragma unroll
    for (int b = 0; b < BB; ++b)
#pragma unroll
        for (int j = 0; j < 2; ++j) acc[b][j] = 0.f;
#pragma unroll
    for (int it = 0; it < 4; ++it) {
        const int d = h * 1024 + it * 256 + lane * 4;
        const float4 nv = *(const float4*)(nw + d);
        const floatx4 u0 = __builtin_nontemporal_load(
            (const floatx4*)(Wo + (size_t)e0 * DD + d));
        const floatx4 u1 = __builtin_nontemporal_load(
            (const floatx4*)(Wo + (size_t)(e0 + 1) * DD + d));
        float4 w0, w1;
        w0.x = u0.x * nv.x; w0.y = u0.y * nv.y; w0.z = u0.z * nv.z; w0.w = u0.w * nv.w;
        w1.x = u1.x * nv.x; w1.y = u1.y * nv.y; w1.z = u1.z * nv.z; w1.w = u1.w * nv.w;
#pragma unroll
        for (int b = 0; b < BB; ++b) {
            const float4 fv = *(const float4*)(fused + (size_t)b * DD + d);
            acc[b][0] += dot4(fv, w0);
            acc[b][1] += dot4(fv, w1);
        }
    }
#pragma unroll
    for (int b = 0; b < BB; ++b)
#pragma unroll
        for (int j = 0; j < 2; ++j)
            for (int off = 32; off; off >>= 1) acc[b][j] += __shfl_down(acc[b][j], off);
    __shared__ float sred1[2][2][BB][2];
    if (lane == 0) {
#pragma unroll
        for (int b = 0; b < BB; ++b)
#pragma unroll
            for (int j = 0; j < 2; ++j) sred1[p][h][b][j] = acc[b][j];
    }
    __syncthreads();
    if (h == 0 && lane == 0) {
#pragma unroll
        for (int b = 0; b < BB; ++b)
#pragma unroll
            for (int j = 0; j < 2; ++j)
                o[b * DD + e0 + j] = (sred1[p][0][b][j] + sred1[p][1][b][j]) * sscale[b];
    }
}

// ---------------------------------------------------------------------------
// K5: out[b,n,e] = x[b,n,e] + o[b,e]. Cacheable x read, nontemporal store.
__global__ __launch_bounds__(256) void k_add(const float* __restrict__ x,
                                             const float* __restrict__ o,
                                             float* __restrict__ out) {
    const size_t total4 = (size_t)BB * NN * DD / 4;   // 2^22
    const floatx4* x4 = (const floatx4*)x;
    const floatx4* o4 = (const floatx4*)o;
    floatx4* out4 = (floatx4*)out;
    for (size_t f = (size_t)blockIdx.x * 256 + threadIdx.x; f < total4;
         f += (size_t)2048 * 256) {
        const int e4 = (int)(f & (DD / 4 - 1));
        const int b = (int)(f >> 21);                 // NN*DD/4 = 2^21
        const floatx4 xv = x4[f];                     // cacheable read
        const floatx4 ov = o4[b * (DD / 4) + e4];
        const floatx4 r = xv + ov;
        __builtin_nontemporal_store(r, &out4[f]);     // streaming write
    }
}

extern "C" void kernel_launch(void* const* d_in, const int* in_sizes, int n_in,
                              void* d_out, int out_size, void* d_ws, size_t ws_size,
                              hipStream_t stream) {
    const float* x  = (const float*)d_in[0];
    const float* te = (const float*)d_in[1];
    const float* Wc = (const float*)d_in[2];
    // d_in[3] = Wq, d_in[4] = Wk : unused (softmax over a single key == 1)
    const float* Wv = (const float*)d_in[5];
    const float* Wo = (const float*)d_in[6];
    const float* bw = (const float*)d_in[7];
    const float* sg = (const float*)d_in[8];
    const float* nw = (const float*)d_in[9];
    const int* isur = (const int*)d_in[10];
    float* out = (float*)d_out;

    float* ws     = (float*)d_ws;
    float* cw     = ws;                       // B*L*C  = 3072 (pad to 4096)
    float* cr     = ws + 4096;                // B*C*D  = 24576
    float* fusedv = ws + 4096 + 24576;        // B*D    = 4096
    float* o      = fusedv + 4096;            // B*D    = 4096

    hipLaunchKernelGGL(k_cluster, dim3(BB * LL), dim3(256), 0, stream, te, Wc, cw);
    hipLaunchKernelGGL(k_creps,   dim3(BB * 64), dim3(256), 0, stream, te, cw, cr);
    hipLaunchKernelGGL(k_vfuse,   dim3(DD / 4), dim3(256), 0, stream,
                       cr, Wv, bw, sg, isur, fusedv);
    hipLaunchKernelGGL(k_rmsout,  dim3(DD / 4), dim3(256), 0, stream,
                       fusedv, nw, Wo, o);
    hipLaunchKernelGGL(k_add,     dim3(2048), dim3(256), 0, stream, x, o, out);
}

// Round 11
// 51.438 us; speedup vs baseline: 3.4556x; 1.0415x over previous
//
#include <hip/hip_runtime.h>
#include <hip/hip_bf16.h>

#define BB 2
#define NN 4096
#define LL 256
#define DD 2048
#define CC 6
#define EPSF 1e-6f

typedef float floatx4 __attribute__((ext_vector_type(4)));

__device__ __forceinline__ float dot4(float4 a, float4 b) {
    return a.x * b.x + a.y * b.y + a.z * b.z + a.w * b.w;
}

// ---------------------------------------------------------------------------
// K1: cluster softmax -> cw (B,L,C). One block per (b,l) row. (R8-proven)
__global__ __launch_bounds__(256) void k_cluster(const float* __restrict__ te,
                                                 const float* __restrict__ Wc,
                                                 float* __restrict__ cw) {
    const int tid = threadIdx.x;
    const int row = blockIdx.x;              // b*LL + l
    const float4* t4 = (const float4*)(te + (size_t)row * DD);
    float p[CC];
#pragma unroll
    for (int c = 0; c < CC; ++c) p[c] = 0.f;
#pragma unroll
    for (int it = 0; it < 2; ++it) {
        const int i = it * 256 + tid;
        const float4 xv = t4[i];
#pragma unroll
        for (int c = 0; c < CC; ++c)
            p[c] += dot4(xv, ((const float4*)(Wc + (size_t)c * DD))[i]);
    }
#pragma unroll
    for (int c = 0; c < CC; ++c)
        for (int off = 32; off; off >>= 1) p[c] += __shfl_down(p[c], off);
    __shared__ float sred[4][CC];
    const int lane = tid & 63, wid = tid >> 6;
    if (lane == 0) {
#pragma unroll
        for (int c = 0; c < CC; ++c) sred[wid][c] = p[c];
    }
    __syncthreads();
    if (tid == 0) {
        float lg[CC], m = -1e30f;
#pragma unroll
        for (int c = 0; c < CC; ++c) {
            lg[c] = sred[0][c] + sred[1][c] + sred[2][c] + sred[3][c];
            m = fmaxf(m, lg[c]);
        }
        float s = 0.f;
#pragma unroll
        for (int c = 0; c < CC; ++c) { lg[c] = __expf(lg[c] - m); s += lg[c]; }
        const float inv = 1.f / s;
#pragma unroll
        for (int c = 0; c < CC; ++c) cw[row * CC + c] = lg[c] * inv;
    }
}

// ---------------------------------------------------------------------------
// K2: concept_reps -> cr (B,C,D). 128 blocks. (R8-proven, cached loads)
__global__ __launch_bounds__(256) void k_creps(const float* __restrict__ te,
                                               const float* __restrict__ cw,
                                               float* __restrict__ cr) {
    const int tid = threadIdx.x;
    const int b = blockIdx.x >> 6;
    const int d0 = (blockIdx.x & 63) * 32;
    const int dl = tid & 31;                 // d within slice
    const int lc = tid >> 5;                 // l-chunk 0..7
    __shared__ float scw[LL * CC];           // 6 KB
    __shared__ float sacc[8][32][CC];        // 6 KB
    for (int i = tid; i < LL * CC; i += 256) scw[i] = cw[b * LL * CC + i];
    __syncthreads();
    float acc[CC];
#pragma unroll
    for (int c = 0; c < CC; ++c) acc[c] = 0.f;
    const float* tb = te + ((size_t)b * LL + lc * 32) * DD + d0 + dl;
    for (int l = 0; l < 32; ++l) {
        const float xv = tb[(size_t)l * DD];
        const int gl = lc * 32 + l;
#pragma unroll
        for (int c = 0; c < CC; ++c) acc[c] = fmaf(scw[gl * CC + c], xv, acc[c]);
    }
#pragma unroll
    for (int c = 0; c < CC; ++c) sacc[lc][dl][c] = acc[c];
    __syncthreads();
    if (tid < 32) {
#pragma unroll
        for (int c = 0; c < CC; ++c) {
            float s = 0.f;
#pragma unroll
            for (int k = 0; k < 8; ++k) s += sacc[k][tid][c];
            cr[((size_t)b * CC + c) * DD + d0 + tid] = s;
        }
    }
}

// ---------------------------------------------------------------------------
// K3: v = cr.Wv^T + blend-softmax + unbiased-var gate -> fused (B,D).
//     512 blocks; wave = (pair p, half h). Also emits per-block partial
//     sum-of-squares of fused -> ssqpart[(bid*2+p)*2+b] (for RMS in K4).
__global__ __launch_bounds__(256) void k_vfuse(const float* __restrict__ cr,
                                               const float* __restrict__ Wv,
                                               const float* __restrict__ blendw,
                                               const float* __restrict__ sgate,
                                               const int* __restrict__ issur,
                                               float* __restrict__ fused,
                                               float* __restrict__ ssqpart) {
    const int tid = threadIdx.x;
    const int lane = tid & 63, wid = tid >> 6;
    const int p = wid >> 1, h = wid & 1;
    const int e0 = blockIdx.x * 4 + p * 2;   // this pair's 2 e-columns
    float acc[BB][2][CC];
#pragma unroll
    for (int b = 0; b < BB; ++b)
#pragma unroll
        for (int j = 0; j < 2; ++j)
#pragma unroll
            for (int c = 0; c < CC; ++c) acc[b][j][c] = 0.f;
#pragma unroll
    for (int it = 0; it < 4; ++it) {
        const int d = h * 1024 + it * 256 + lane * 4;
        const float4 w0 = *(const float4*)(Wv + (size_t)e0 * DD + d);
        const float4 w1 = *(const float4*)(Wv + (size_t)(e0 + 1) * DD + d);
#pragma unroll
        for (int b = 0; b < BB; ++b)
#pragma unroll
            for (int c = 0; c < CC; ++c) {
                const float4 cv = *(const float4*)(cr + ((size_t)b * CC + c) * DD + d);
                acc[b][0][c] += dot4(cv, w0);
                acc[b][1][c] += dot4(cv, w1);
            }
    }
#pragma unroll
    for (int b = 0; b < BB; ++b)
#pragma unroll
        for (int j = 0; j < 2; ++j)
#pragma unroll
            for (int c = 0; c < CC; ++c)
                for (int off = 32; off; off >>= 1)
                    acc[b][j][c] += __shfl_down(acc[b][j][c], off);
    __shared__ float sred[2][2][BB][2][CC];
    if (lane == 0) {
#pragma unroll
        for (int b = 0; b < BB; ++b)
#pragma unroll
            for (int j = 0; j < 2; ++j)
#pragma unroll
                for (int c = 0; c < CC; ++c) sred[p][h][b][j][c] = acc[b][j][c];
    }
    __syncthreads();
    if (h == 0 && lane == 0) {
        float bw[CC], m = -1e30f;
#pragma unroll
        for (int c = 0; c < CC; ++c) { bw[c] = blendw[c]; m = fmaxf(m, bw[c]); }
        float s = 0.f;
#pragma unroll
        for (int c = 0; c < CC; ++c) { bw[c] = __expf(bw[c] - m); s += bw[c]; }
        const float inv = 1.f / s;
#pragma unroll
        for (int c = 0; c < CC; ++c) bw[c] *= inv;
        const float gate = 1.f / (1.f + __expf(-sgate[0]));
        const int sur = issur[0];
#pragma unroll
        for (int b = 0; b < BB; ++b) {
            float ssqc = 0.f;
#pragma unroll
            for (int j = 0; j < 2; ++j) {
                float vv[CC];
#pragma unroll
                for (int c = 0; c < CC; ++c)
                    vv[c] = sred[p][0][b][j][c] + sred[p][1][b][j][c];
                float f = 0.f, mean = 0.f;
#pragma unroll
                for (int c = 0; c < CC; ++c) { f = fmaf(bw[c], vv[c], f); mean += vv[c]; }
                mean *= (1.f / CC);
                float var = 0.f;
#pragma unroll
                for (int c = 0; c < CC; ++c) {
                    const float dv = vv[c] - mean;
                    var = fmaf(dv, dv, var);
                }
                var *= (1.f / (CC - 1));     // ddof=1
                if (sur) f = fmaf(gate * var, 0.3f, f);
                fused[b * DD + e0 + j] = f;
                ssqc = fmaf(f, f, ssqc);
            }
            ssqpart[(blockIdx.x * 2 + p) * 2 + b] = ssqc;
        }
    }
}

// ---------------------------------------------------------------------------
// K4: RMS scales from ssqpart partials + out-proj GEMV. (R8 layout)
__global__ __launch_bounds__(256) void k_rmsout(const float* __restrict__ fused,
                                                const float* __restrict__ ssqpart,
                                                const float* __restrict__ nw,
                                                const float* __restrict__ Wo,
                                                float* __restrict__ o) {
    const int tid = threadIdx.x;
    const int lane = tid & 63, wid = tid >> 6;
    // --- sum 2048 partials (index parity = b); each thread one parity ---
    float ss[BB];
#pragma unroll
    for (int b = 0; b < BB; ++b) ss[b] = 0.f;
#pragma unroll
    for (int k = 0; k < 8; ++k) {
        const int i = k * 256 + tid;
        ss[i & 1] += ssqpart[i];
    }
#pragma unroll
    for (int b = 0; b < BB; ++b)
        for (int off = 32; off; off >>= 1) ss[b] += __shfl_down(ss[b], off);
    __shared__ float sred0[4][BB];
    __shared__ float sscale[BB];
    if (lane == 0) {
#pragma unroll
        for (int b = 0; b < BB; ++b) sred0[wid][b] = ss[b];
    }
    __syncthreads();
    if (tid == 0) {
#pragma unroll
        for (int b = 0; b < BB; ++b) {
            const float tot = sred0[0][b] + sred0[1][b] + sred0[2][b] + sred0[3][b];
            sscale[b] = rsqrtf(tot * (1.f / DD) + EPSF);
        }
    }
    __syncthreads();
    const int p = wid >> 1, h = wid & 1;
    const int e0 = blockIdx.x * 4 + p * 2;
    float acc[BB][2];
#pragma unroll
    for (int b = 0; b < BB; ++b)
#pragma unroll
        for (int j = 0; j < 2; ++j) acc[b][j] = 0.f;
#pragma unroll
    for (int it = 0; it < 4; ++it) {
        const int d = h * 1024 + it * 256 + lane * 4;
        const float4 nv = *(const float4*)(nw + d);
        float4 w0 = *(const float4*)(Wo + (size_t)e0 * DD + d);
        float4 w1 = *(const float4*)(Wo + (size_t)(e0 + 1) * DD + d);
        w0.x *= nv.x; w0.y *= nv.y; w0.z *= nv.z; w0.w *= nv.w;
        w1.x *= nv.x; w1.y *= nv.y; w1.z *= nv.z; w1.w *= nv.w;
#pragma unroll
        for (int b = 0; b < BB; ++b) {
            const float4 fv = *(const float4*)(fused + (size_t)b * DD + d);
            acc[b][0] += dot4(fv, w0);
            acc[b][1] += dot4(fv, w1);
        }
    }
#pragma unroll
    for (int b = 0; b < BB; ++b)
#pragma unroll
        for (int j = 0; j < 2; ++j)
            for (int off = 32; off; off >>= 1) acc[b][j] += __shfl_down(acc[b][j], off);
    __shared__ float sred1[2][2][BB][2];
    if (lane == 0) {
#pragma unroll
        for (int b = 0; b < BB; ++b)
#pragma unroll
            for (int j = 0; j < 2; ++j) sred1[p][h][b][j] = acc[b][j];
    }
    __syncthreads();
    if (h == 0 && lane == 0) {
#pragma unroll
        for (int b = 0; b < BB; ++b)
#pragma unroll
            for (int j = 0; j < 2; ++j)
                o[b * DD + e0 + j] = (sred1[p][0][b][j] + sred1[p][1][b][j]) * sscale[b];
    }
}

// ---------------------------------------------------------------------------
// K5: out[b,n,e] = x[b,n,e] + o[b,e]. Cacheable x read, nontemporal store.
__global__ __launch_bounds__(256) void k_add(const float* __restrict__ x,
                                             const float* __restrict__ o,
                                             float* __restrict__ out) {
    const size_t total4 = (size_t)BB * NN * DD / 4;   // 2^22
    const floatx4* x4 = (const floatx4*)x;
    const floatx4* o4 = (const floatx4*)o;
    floatx4* out4 = (floatx4*)out;
    for (size_t f = (size_t)blockIdx.x * 256 + threadIdx.x; f < total4;
         f += (size_t)2048 * 256) {
        const int e4 = (int)(f & (DD / 4 - 1));
        const int b = (int)(f >> 21);                 // NN*DD/4 = 2^21
        const floatx4 xv = x4[f];                     // cacheable read
        const floatx4 ov = o4[b * (DD / 4) + e4];
        const floatx4 r = xv + ov;
        __builtin_nontemporal_store(r, &out4[f]);     // streaming write
    }
}

extern "C" void kernel_launch(void* const* d_in, const int* in_sizes, int n_in,
                              void* d_out, int out_size, void* d_ws, size_t ws_size,
                              hipStream_t stream) {
    const float* x  = (const float*)d_in[0];
    const float* te = (const float*)d_in[1];
    const float* Wc = (const float*)d_in[2];
    // d_in[3] = Wq, d_in[4] = Wk : unused (softmax over a single key == 1)
    const float* Wv = (const float*)d_in[5];
    const float* Wo = (const float*)d_in[6];
    const float* bw = (const float*)d_in[7];
    const float* sg = (const float*)d_in[8];
    const float* nw = (const float*)d_in[9];
    const int* isur = (const int*)d_in[10];
    float* out = (float*)d_out;

    float* ws      = (float*)d_ws;
    float* cw      = ws;                      // B*L*C  = 3072 (pad to 4096)
    float* cr      = ws + 4096;               // B*C*D  = 24576
    float* fusedv  = ws + 4096 + 24576;       // B*D    = 4096
    float* o       = fusedv + 4096;           // B*D    = 4096
    float* ssqpart = o + 4096;                // 512 blocks * 2p * 2b = 2048

    hipLaunchKernelGGL(k_cluster, dim3(BB * LL), dim3(256), 0, stream, te, Wc, cw);
    hipLaunchKernelGGL(k_creps,   dim3(BB * 64), dim3(256), 0, stream, te, cw, cr);
    hipLaunchKernelGGL(k_vfuse,   dim3(DD / 4), dim3(256), 0, stream,
                       cr, Wv, bw, sg, isur, fusedv, ssqpart);
    hipLaunchKernelGGL(k_rmsout,  dim3(DD / 4), dim3(256), 0, stream,
                       fusedv, ssqpart, nw, Wo, o);
    hipLaunchKernelGGL(k_add,     dim3(2048), dim3(256), 0, stream, x, o, out);
}

// Round 12
// 50.546 us; speedup vs baseline: 3.5166x; 1.0176x over previous
//
#include <hip/hip_runtime.h>
#include <hip/hip_bf16.h>

#define BB 2
#define NN 4096
#define LL 256
#define DD 2048
#define CC 6
#define EPSF 1e-6f

typedef float floatx4 __attribute__((ext_vector_type(4)));

__device__ __forceinline__ float dot4(float4 a, float4 b) {
    return a.x * b.x + a.y * b.y + a.z * b.z + a.w * b.w;
}

// ---------------------------------------------------------------------------
// K1: cluster softmax -> cw (B,L,C). One block per (b,l) row.
__global__ __launch_bounds__(256) void k_cluster(const float* __restrict__ te,
                                                 const float* __restrict__ Wc,
                                                 float* __restrict__ cw) {
    const int tid = threadIdx.x;
    const int row = blockIdx.x;              // b*LL + l
    const float4* t4 = (const float4*)(te + (size_t)row * DD);
    float p[CC];
#pragma unroll
    for (int c = 0; c < CC; ++c) p[c] = 0.f;
#pragma unroll
    for (int it = 0; it < 2; ++it) {
        const int i = it * 256 + tid;
        const float4 xv = t4[i];
#pragma unroll
        for (int c = 0; c < CC; ++c)
            p[c] += dot4(xv, ((const float4*)(Wc + (size_t)c * DD))[i]);
    }
#pragma unroll
    for (int c = 0; c < CC; ++c)
        for (int off = 32; off; off >>= 1) p[c] += __shfl_down(p[c], off);
    __shared__ float sred[4][CC];
    const int lane = tid & 63, wid = tid >> 6;
    if (lane == 0) {
#pragma unroll
        for (int c = 0; c < CC; ++c) sred[wid][c] = p[c];
    }
    __syncthreads();
    if (tid == 0) {
        float lg[CC], m = -1e30f;
#pragma unroll
        for (int c = 0; c < CC; ++c) {
            lg[c] = sred[0][c] + sred[1][c] + sred[2][c] + sred[3][c];
            m = fmaxf(m, lg[c]);
        }
        float s = 0.f;
#pragma unroll
        for (int c = 0; c < CC; ++c) { lg[c] = __expf(lg[c] - m); s += lg[c]; }
        const float inv = 1.f / s;
#pragma unroll
        for (int c = 0; c < CC; ++c) cw[row * CC + c] = lg[c] * inv;
    }
}

// ---------------------------------------------------------------------------
// K2: concept_reps -> cr (B,C,D). 128 blocks; block = (b, 32-wide d-slice),
//     8 l-chunks of 32 across the block, LDS reduce.
__global__ __launch_bounds__(256) void k_creps(const float* __restrict__ te,
                                               const float* __restrict__ cw,
                                               float* __restrict__ cr) {
    const int tid = threadIdx.x;
    const int b = blockIdx.x >> 6;
    const int d0 = (blockIdx.x & 63) * 32;
    const int dl = tid & 31;                 // d within slice
    const int lc = tid >> 5;                 // l-chunk 0..7
    __shared__ float scw[LL * CC];           // 6 KB
    __shared__ float sacc[8][32][CC];        // 6 KB
    for (int i = tid; i < LL * CC; i += 256) scw[i] = cw[b * LL * CC + i];
    __syncthreads();
    float acc[CC];
#pragma unroll
    for (int c = 0; c < CC; ++c) acc[c] = 0.f;
    const float* tb = te + ((size_t)b * LL + lc * 32) * DD + d0 + dl;
    for (int l = 0; l < 32; ++l) {
        const float xv = tb[(size_t)l * DD];
        const int gl = lc * 32 + l;
#pragma unroll
        for (int c = 0; c < CC; ++c) acc[c] = fmaf(scw[gl * CC + c], xv, acc[c]);
    }
#pragma unroll
    for (int c = 0; c < CC; ++c) sacc[lc][dl][c] = acc[c];
    __syncthreads();
    if (tid < 32) {
#pragma unroll
        for (int c = 0; c < CC; ++c) {
            float s = 0.f;
#pragma unroll
            for (int k = 0; k < 8; ++k) s += sacc[k][tid][c];
            cr[((size_t)b * CC + c) * DD + d0 + tid] = s;
        }
    }
}

// ---------------------------------------------------------------------------
// K3: v = cr.Wv^T + blend-softmax + unbiased-var gate -> fused (B,D).
//     512 blocks; wave = (pair p, half h): 2 e-columns over half of D.
//     Halves combined in LDS -> cr L2 traffic halved at full 2-blocks/CU.
__global__ __launch_bounds__(256) void k_vfuse(const float* __restrict__ cr,
                                               const float* __restrict__ Wv,
                                               const float* __restrict__ blendw,
                                               const float* __restrict__ sgate,
                                               const int* __restrict__ issur,
                                               float* __restrict__ fused) {
    const int tid = threadIdx.x;
    const int lane = tid & 63, wid = tid >> 6;
    const int p = wid >> 1, h = wid & 1;
    const int e0 = blockIdx.x * 4 + p * 2;   // this pair's 2 e-columns
    float acc[BB][2][CC];
#pragma unroll
    for (int b = 0; b < BB; ++b)
#pragma unroll
        for (int j = 0; j < 2; ++j)
#pragma unroll
            for (int c = 0; c < CC; ++c) acc[b][j][c] = 0.f;
#pragma unroll
    for (int it = 0; it < 4; ++it) {
        const int d = h * 1024 + it * 256 + lane * 4;
        const float4 w0 = *(const float4*)(Wv + (size_t)e0 * DD + d);
        const float4 w1 = *(const float4*)(Wv + (size_t)(e0 + 1) * DD + d);
#pragma unroll
        for (int b = 0; b < BB; ++b)
#pragma unroll
            for (int c = 0; c < CC; ++c) {
                const float4 cv = *(const float4*)(cr + ((size_t)b * CC + c) * DD + d);
                acc[b][0][c] += dot4(cv, w0);
                acc[b][1][c] += dot4(cv, w1);
            }
    }
#pragma unroll
    for (int b = 0; b < BB; ++b)
#pragma unroll
        for (int j = 0; j < 2; ++j)
#pragma unroll
            for (int c = 0; c < CC; ++c)
                for (int off = 32; off; off >>= 1)
                    acc[b][j][c] += __shfl_down(acc[b][j][c], off);
    __shared__ float sred[2][2][BB][2][CC];
    if (lane == 0) {
#pragma unroll
        for (int b = 0; b < BB; ++b)
#pragma unroll
            for (int j = 0; j < 2; ++j)
#pragma unroll
                for (int c = 0; c < CC; ++c) sred[p][h][b][j][c] = acc[b][j][c];
    }
    __syncthreads();
    if (h == 0 && lane == 0) {
        float bw[CC], m = -1e30f;
#pragma unroll
        for (int c = 0; c < CC; ++c) { bw[c] = blendw[c]; m = fmaxf(m, bw[c]); }
        float s = 0.f;
#pragma unroll
        for (int c = 0; c < CC; ++c) { bw[c] = __expf(bw[c] - m); s += bw[c]; }
        const float inv = 1.f / s;
#pragma unroll
        for (int c = 0; c < CC; ++c) bw[c] *= inv;
        const float gate = 1.f / (1.f + __expf(-sgate[0]));
        const int sur = issur[0];
#pragma unroll
        for (int b = 0; b < BB; ++b)
#pragma unroll
            for (int j = 0; j < 2; ++j) {
                float vv[CC];
#pragma unroll
                for (int c = 0; c < CC; ++c)
                    vv[c] = sred[p][0][b][j][c] + sred[p][1][b][j][c];
                float f = 0.f, mean = 0.f;
#pragma unroll
                for (int c = 0; c < CC; ++c) { f = fmaf(bw[c], vv[c], f); mean += vv[c]; }
                mean *= (1.f / CC);
                float var = 0.f;
#pragma unroll
                for (int c = 0; c < CC; ++c) {
                    const float dv = vv[c] - mean;
                    var = fmaf(dv, dv, var);
                }
                var *= (1.f / (CC - 1));     // ddof=1
                if (sur) f = fmaf(gate * var, 0.3f, f);
                fused[b * DD + e0 + j] = f;
            }
    }
}

// ---------------------------------------------------------------------------
// K4: RMS scales (per-block recompute from L2-resident fused) + out-proj GEMV.
__global__ __launch_bounds__(256) void k_rmsout(const float* __restrict__ fused,
                                                const float* __restrict__ nw,
                                                const float* __restrict__ Wo,
                                                float* __restrict__ o) {
    const int tid = threadIdx.x;
    const int lane = tid & 63, wid = tid >> 6;
    float ss[BB];
#pragma unroll
    for (int b = 0; b < BB; ++b) ss[b] = 0.f;
#pragma unroll
    for (int k = 0; k < DD / 256; ++k) {
        const int d = k * 256 + tid;
#pragma unroll
        for (int b = 0; b < BB; ++b) {
            const float v = fused[b * DD + d];
            ss[b] = fmaf(v, v, ss[b]);
        }
    }
#pragma unroll
    for (int b = 0; b < BB; ++b)
        for (int off = 32; off; off >>= 1) ss[b] += __shfl_down(ss[b], off);
    __shared__ float sred0[4][BB];
    __shared__ float sscale[BB];
    if (lane == 0) {
#pragma unroll
        for (int b = 0; b < BB; ++b) sred0[wid][b] = ss[b];
    }
    __syncthreads();
    if (tid == 0) {
#pragma unroll
        for (int b = 0; b < BB; ++b) {
            const float tot = sred0[0][b] + sred0[1][b] + sred0[2][b] + sred0[3][b];
            sscale[b] = rsqrtf(tot * (1.f / DD) + EPSF);
        }
    }
    __syncthreads();
    const int p = wid >> 1, h = wid & 1;
    const int e0 = blockIdx.x * 4 + p * 2;
    float acc[BB][2];
#pragma unroll
    for (int b = 0; b < BB; ++b)
#pragma unroll
        for (int j = 0; j < 2; ++j) acc[b][j] = 0.f;
#pragma unroll
    for (int it = 0; it < 4; ++it) {
        const int d = h * 1024 + it * 256 + lane * 4;
        const float4 nv = *(const float4*)(nw + d);
        float4 w0 = *(const float4*)(Wo + (size_t)e0 * DD + d);
        float4 w1 = *(const float4*)(Wo + (size_t)(e0 + 1) * DD + d);
        w0.x *= nv.x; w0.y *= nv.y; w0.z *= nv.z; w0.w *= nv.w;
        w1.x *= nv.x; w1.y *= nv.y; w1.z *= nv.z; w1.w *= nv.w;
#pragma unroll
        for (int b = 0; b < BB; ++b) {
            const float4 fv = *(const float4*)(fused + (size_t)b * DD + d);
            acc[b][0] += dot4(fv, w0);
            acc[b][1] += dot4(fv, w1);
        }
    }
#pragma unroll
    for (int b = 0; b < BB; ++b)
#pragma unroll
        for (int j = 0; j < 2; ++j)
            for (int off = 32; off; off >>= 1) acc[b][j] += __shfl_down(acc[b][j], off);
    __shared__ float sred1[2][2][BB][2];
    if (lane == 0) {
#pragma unroll
        for (int b = 0; b < BB; ++b)
#pragma unroll
            for (int j = 0; j < 2; ++j) sred1[p][h][b][j] = acc[b][j];
    }
    __syncthreads();
    if (h == 0 && lane == 0) {
#pragma unroll
        for (int b = 0; b < BB; ++b)
#pragma unroll
            for (int j = 0; j < 2; ++j)
                o[b * DD + e0 + j] = (sred1[p][0][b][j] + sred1[p][1][b][j]) * sscale[b];
    }
}

// ---------------------------------------------------------------------------
// K5: out[b,n,e] = x[b,n,e] + o[b,e].
//     x load CACHEABLE (L3-resident across replays); out store NONTEMPORAL
//     (write-once stream; avoid evicting x/Wv/Wo from L3 between replays).
__global__ __launch_bounds__(256) void k_add(const float* __restrict__ x,
                                             const float* __restrict__ o,
                                             float* __restrict__ out) {
    const size_t total4 = (size_t)BB * NN * DD / 4;   // 2^22
    const floatx4* x4 = (const floatx4*)x;
    const floatx4* o4 = (const floatx4*)o;
    floatx4* out4 = (floatx4*)out;
    for (size_t f = (size_t)blockIdx.x * 256 + threadIdx.x; f < total4;
         f += (size_t)2048 * 256) {
        const int e4 = (int)(f & (DD / 4 - 1));
        const int b = (int)(f >> 21);                 // NN*DD/4 = 2^21
        const floatx4 xv = x4[f];                     // cacheable read
        const floatx4 ov = o4[b * (DD / 4) + e4];
        const floatx4 r = xv + ov;
        __builtin_nontemporal_store(r, &out4[f]);     // streaming write
    }
}

extern "C" void kernel_launch(void* const* d_in, const int* in_sizes, int n_in,
                              void* d_out, int out_size, void* d_ws, size_t ws_size,
                              hipStream_t stream) {
    const float* x  = (const float*)d_in[0];
    const float* te = (const float*)d_in[1];
    const float* Wc = (const float*)d_in[2];
    // d_in[3] = Wq, d_in[4] = Wk : unused (softmax over a single key == 1)
    const float* Wv = (const float*)d_in[5];
    const float* Wo = (const float*)d_in[6];
    const float* bw = (const float*)d_in[7];
    const float* sg = (const float*)d_in[8];
    const float* nw = (const float*)d_in[9];
    const int* isur = (const int*)d_in[10];
    float* out = (float*)d_out;

    float* ws     = (float*)d_ws;
    float* cw     = ws;                       // B*L*C  = 3072 (pad to 4096)
    float* cr     = ws + 4096;                // B*C*D  = 24576
    float* fusedv = ws + 4096 + 24576;        // B*D    = 4096
    float* o      = fusedv + 4096;            // B*D    = 4096

    hipLaunchKernelGGL(k_cluster, dim3(BB * LL), dim3(256), 0, stream, te, Wc, cw);
    hipLaunchKernelGGL(k_creps,   dim3(BB * 64), dim3(256), 0, stream, te, cw, cr);
    hipLaunchKernelGGL(k_vfuse,   dim3(DD / 4), dim3(256), 0, stream,
                       cr, Wv, bw, sg, isur, fusedv);
    hipLaunchKernelGGL(k_rmsout,  dim3(DD / 4), dim3(256), 0, stream,
                       fusedv, nw, Wo, o);
    hipLaunchKernelGGL(k_add,     dim3(2048), dim3(256), 0, stream, x, o, out);
}